// Round 3
// baseline (24592.952 us; speedup 1.0000x reference)
//
#include <hip/hip_runtime.h>
#include <math.h>

#define BB 32
#define TT 512
#define DD 512
#define UU 512
#define G3 1536   // 3*U
#define CHUNK 64  // time steps per xg chunk

__device__ __forceinline__ float hsig(float x) {
    return fminf(fmaxf(fmaf(0.2f, x, 0.5f), 0.0f), 1.0f);
}

// ---------------------------------------------------------------------------
// Kernel A: x_gates chunk GEMM (proven in round 2, unchanged).
// xgc[dir][i][b][n] = sum_k x[b][t_phys][k] * W_dir[k][n] + bias_dir[n]
// ---------------------------------------------------------------------------
__global__ __launch_bounds__(256) void xg_gemm(
    const float* __restrict__ x,
    const float* __restrict__ Wf, const float* __restrict__ bf,
    const float* __restrict__ Wb, const float* __restrict__ bb,
    float* __restrict__ xgc, int t0)
{
    const int dir = blockIdx.z;
    const int n0  = blockIdx.x * 64;
    const int m0  = blockIdx.y * 128;
    const float* W    = dir ? Wb : Wf;
    const float* bias = dir ? bb : bf;

    __shared__ float As[16][132];
    __shared__ float Bs[16][64];

    const int tid = threadIdx.x;
    const int tx = tid & 15, ty = tid >> 4;

    float acc[8][4];
    #pragma unroll
    for (int i = 0; i < 8; ++i)
        #pragma unroll
        for (int q = 0; q < 4; ++q) acc[i][q] = 0.f;

    const int lmr = tid >> 2;
    const int ak4 = (tid & 3) * 4;
    const float* arow0;
    const float* arow1;
    {
        int m = m0 + lmr;
        int b = m & 31, i = m >> 5;
        int tp = dir ? (TT - 1 - t0 - i) : (t0 + i);
        arow0 = x + ((size_t)b * TT + tp) * DD;
        m = m0 + lmr + 64;
        b = m & 31; i = m >> 5;
        tp = dir ? (TT - 1 - t0 - i) : (t0 + i);
        arow1 = x + ((size_t)b * TT + tp) * DD;
    }
    const float* bsrc = W + (size_t)(tid >> 4) * G3 + n0 + (tid & 15) * 4;

    for (int k0 = 0; k0 < DD; k0 += 16) {
        float4 a0 = *(const float4*)(arow0 + k0 + ak4);
        float4 a1 = *(const float4*)(arow1 + k0 + ak4);
        float4 bv = *(const float4*)(bsrc + (size_t)k0 * G3);
        __syncthreads();
        As[ak4 + 0][lmr] = a0.x;  As[ak4 + 1][lmr] = a0.y;
        As[ak4 + 2][lmr] = a0.z;  As[ak4 + 3][lmr] = a0.w;
        As[ak4 + 0][lmr + 64] = a1.x;  As[ak4 + 1][lmr + 64] = a1.y;
        As[ak4 + 2][lmr + 64] = a1.z;  As[ak4 + 3][lmr + 64] = a1.w;
        *(float4*)&Bs[tid >> 4][(tid & 15) * 4] = bv;
        __syncthreads();
        #pragma unroll
        for (int kk = 0; kk < 16; ++kk) {
            float4 b4 = *(const float4*)&Bs[kk][tx * 4];
            #pragma unroll
            for (int i = 0; i < 8; ++i) {
                float a = As[kk][ty * 8 + i];
                acc[i][0] = fmaf(a, b4.x, acc[i][0]);
                acc[i][1] = fmaf(a, b4.y, acc[i][1]);
                acc[i][2] = fmaf(a, b4.z, acc[i][2]);
                acc[i][3] = fmaf(a, b4.w, acc[i][3]);
            }
        }
    }

    float4 bv = *(const float4*)(bias + n0 + tx * 4);
    #pragma unroll
    for (int i = 0; i < 8; ++i) {
        int m = m0 + ty * 8 + i;
        float4 o;
        o.x = acc[i][0] + bv.x;  o.y = acc[i][1] + bv.y;
        o.z = acc[i][2] + bv.z;  o.w = acc[i][3] + bv.w;
        *(float4*)(xgc + ((size_t)dir * (CHUNK * BB) + m) * G3 + n0 + tx * 4) = o;
    }
}

// ---------------------------------------------------------------------------
// Group barrier: 32 WGs, monotone epoch, agent scope.  blk 32g..32g+31 = group.
// ---------------------------------------------------------------------------
__device__ __forceinline__ void group_barrier(unsigned* arrive, unsigned* epoch,
                                              unsigned serial) {
    __syncthreads();
    if (threadIdx.x == 0) {
        __threadfence();
        unsigned old = __hip_atomic_fetch_add(arrive, 1u, __ATOMIC_ACQ_REL,
                                              __HIP_MEMORY_SCOPE_AGENT);
        if ((old & 31u) == 31u) {
            __hip_atomic_store(epoch, serial + 1u, __ATOMIC_RELEASE,
                               __HIP_MEMORY_SCOPE_AGENT);
        } else {
            while (__hip_atomic_load(epoch, __ATOMIC_ACQUIRE,
                                     __HIP_MEMORY_SCOPE_AGENT) < serial + 1u)
                __builtin_amdgcn_s_sleep(1);
        }
        __threadfence();
    }
    __syncthreads();
}

// ---------------------------------------------------------------------------
// Persistent chunk kernel: 64 time steps of the recurrence.
// 256 WGs x 512 thr, 1 WG/CU (152 KB LDS).  Group = blockIdx>>5 =
// dir(2) x bquad(4), 8 batches each.  WG w (0..31) owns zr-cols
// [w*32,w*32+32) and cand-cols [w*16,w*16+16), staged in LDS col-major
// with row stride 516 (bank spread).
// ---------------------------------------------------------------------------
#define WSTRIDE 516
#define NWCOLS 48
#define P1RED 36   // phase1 partial stride (o<256, ks<32)
#define P2RED 68   // phase2 partial stride (o<128, ks<64)
#define LDS_FLOATS (NWCOLS * WSTRIDE + 8 * WSTRIDE + 9216)

__global__ __launch_bounds__(512, 1) void gru_chunk(
    const float* __restrict__ Uf, const float* __restrict__ Ub,
    const float* __restrict__ xgc,
    float* __restrict__ hbuf, float* __restrict__ zbuf,
    float* __restrict__ rhbuf, unsigned* __restrict__ bars,
    float* __restrict__ out, int c)
{
    extern __shared__ float lds[];
    float* Wl   = lds;                       // 48 cols * 516
    float* hp   = Wl + NWCOLS * WSTRIDE;     // 8 rows * 516
    float* part = hp + 8 * WSTRIDE;          // 9216 floats

    const int tid = threadIdx.x;
    const int g   = blockIdx.x >> 5;   // group 0..7
    const int w   = blockIdx.x & 31;   // WG within group
    const int dir = g >> 2;
    const int b0  = (g & 3) * 8;

    unsigned* bar_arr = bars + g * 64;
    unsigned* bar_ep  = bars + g * 64 + 32;
    const unsigned base = (unsigned)(c * 128);

    const float* U = dir ? Ub : Uf;
    const int n0z = w * 32;
    const int n0c = 1024 + w * 16;

    // ---- stage weights (once per chunk launch) ----
    for (int q = tid; q < 512 * 12; q += 512) {
        int k  = q & 511;
        int jj = q >> 9;                       // 0..11 float4 spans per k-row
        int n  = (jj < 8) ? (n0z + jj * 4) : (n0c + (jj - 8) * 4);
        int cc = (jj < 8) ? jj * 4 : (32 + (jj - 8) * 4);
        float4 v = *(const float4*)(U + (size_t)k * G3 + n);
        float* wc = Wl + (size_t)cc * WSTRIDE + k;
        wc[0]           = v.x;
        wc[WSTRIDE]     = v.y;
        wc[2 * WSTRIDE] = v.z;
        wc[3 * WSTRIDE] = v.w;
    }
    __syncthreads();

    const float* hg_h  = hbuf  + ((size_t)dir * 32 + b0) * 512;
    const float* hg_rh = rhbuf + ((size_t)dir * 32 + b0) * 512;

    for (int i = 0; i < CHUNK; ++i) {
        const int t = c * CHUNK + i;

        // ---- stage h into hp ----
        #pragma unroll
        for (int q = tid; q < 1024; q += 512) {
            int b = q >> 7, k4 = (q & 127) * 4;
            *(float4*)(hp + (size_t)b * WSTRIDE + k4) =
                *(const float4*)(hg_h + (size_t)b * 512 + k4);
        }
        __syncthreads();

        // ---- phase 1 dots: z,r ----
        {
            const int cslot = tid & 7;
            const int bslot = (tid >> 3) & 1;
            const int ks    = tid >> 4;      // 0..31
            const int kb    = ks * 16;
            const float* wp = Wl + (size_t)cslot * WSTRIDE + kb;
            const float* hq = hp + (size_t)(bslot * 4) * WSTRIDE + kb;
            float acc[4][4];
            #pragma unroll
            for (int a = 0; a < 4; ++a)
                #pragma unroll
                for (int b = 0; b < 4; ++b) acc[a][b] = 0.f;
            #pragma unroll
            for (int kk = 0; kk < 16; kk += 4) {
                float4 wv[4], hv[4];
                #pragma unroll
                for (int ci = 0; ci < 4; ++ci)
                    wv[ci] = *(const float4*)(wp + (size_t)ci * (8 * WSTRIDE) + kk);
                #pragma unroll
                for (int bi = 0; bi < 4; ++bi)
                    hv[bi] = *(const float4*)(hq + (size_t)bi * WSTRIDE + kk);
                #pragma unroll
                for (int ci = 0; ci < 4; ++ci)
                    #pragma unroll
                    for (int bi = 0; bi < 4; ++bi) {
                        acc[ci][bi] = fmaf(wv[ci].x, hv[bi].x, acc[ci][bi]);
                        acc[ci][bi] = fmaf(wv[ci].y, hv[bi].y, acc[ci][bi]);
                        acc[ci][bi] = fmaf(wv[ci].z, hv[bi].z, acc[ci][bi]);
                        acc[ci][bi] = fmaf(wv[ci].w, hv[bi].w, acc[ci][bi]);
                    }
            }
            #pragma unroll
            for (int ci = 0; ci < 4; ++ci)
                #pragma unroll
                for (int bi = 0; bi < 4; ++bi) {
                    int o = (bslot * 4 + bi) * 32 + cslot + 8 * ci;
                    part[(size_t)o * P1RED + ks] = acc[ci][bi];
                }
        }
        __syncthreads();

        // ---- phase 1 reduce + gate epilogue ----
        if (tid < 256) {
            const int o = tid;
            const float* pp = part + (size_t)o * P1RED;
            float s = 0.f;
            #pragma unroll
            for (int gq = 0; gq < 8; ++gq) {
                float4 v = *(const float4*)(pp + gq * 4);
                s += (v.x + v.y) + (v.z + v.w);
            }
            const int b_l = o >> 5, c_l = o & 31;
            const int n = n0z + c_l;
            s += xgc[(((size_t)dir * CHUNK + i) * BB + (b0 + b_l)) * G3 + n];
            float gv = hsig(s);
            const size_t row = ((size_t)dir * 32 + b0 + b_l) * 512;
            if (n < 512) zbuf[row + n] = gv;
            else         rhbuf[row + n - 512] = gv * hp[(size_t)b_l * WSTRIDE + (n - 512)];
        }
        group_barrier(bar_arr, bar_ep, base + (unsigned)(i * 2));

        // ---- stage rh into hp ----
        #pragma unroll
        for (int q = tid; q < 1024; q += 512) {
            int b = q >> 7, k4 = (q & 127) * 4;
            *(float4*)(hp + (size_t)b * WSTRIDE + k4) =
                *(const float4*)(hg_rh + (size_t)b * 512 + k4);
        }
        __syncthreads();

        // ---- phase 2 dots: cand ----
        {
            const int cslot = tid & 3;
            const int bslot = (tid >> 2) & 1;
            const int ks    = tid >> 3;      // 0..63
            const int kb    = ks * 8;
            const float* wp = Wl + (size_t)(32 + cslot) * WSTRIDE + kb;
            const float* hq = hp + (size_t)(bslot * 4) * WSTRIDE + kb;
            float acc[4][4];
            #pragma unroll
            for (int a = 0; a < 4; ++a)
                #pragma unroll
                for (int b = 0; b < 4; ++b) acc[a][b] = 0.f;
            #pragma unroll
            for (int kk = 0; kk < 8; kk += 4) {
                float4 wv[4], hv[4];
                #pragma unroll
                for (int ci = 0; ci < 4; ++ci)
                    wv[ci] = *(const float4*)(wp + (size_t)ci * (4 * WSTRIDE) + kk);
                #pragma unroll
                for (int bi = 0; bi < 4; ++bi)
                    hv[bi] = *(const float4*)(hq + (size_t)bi * WSTRIDE + kk);
                #pragma unroll
                for (int ci = 0; ci < 4; ++ci)
                    #pragma unroll
                    for (int bi = 0; bi < 4; ++bi) {
                        acc[ci][bi] = fmaf(wv[ci].x, hv[bi].x, acc[ci][bi]);
                        acc[ci][bi] = fmaf(wv[ci].y, hv[bi].y, acc[ci][bi]);
                        acc[ci][bi] = fmaf(wv[ci].z, hv[bi].z, acc[ci][bi]);
                        acc[ci][bi] = fmaf(wv[ci].w, hv[bi].w, acc[ci][bi]);
                    }
            }
            #pragma unroll
            for (int ci = 0; ci < 4; ++ci)
                #pragma unroll
                for (int bi = 0; bi < 4; ++bi) {
                    int o = (bslot * 4 + bi) * 16 + cslot + 4 * ci;
                    part[(size_t)o * P2RED + ks] = acc[ci][bi];
                }
        }
        __syncthreads();

        // ---- phase 2 reduce + h update + output ----
        if (tid < 128) {
            const int o = tid;
            const float* pp = part + (size_t)o * P2RED;
            float s = 0.f;
            #pragma unroll
            for (int gq = 0; gq < 16; ++gq) {
                float4 v = *(const float4*)(pp + gq * 4);
                s += (v.x + v.y) + (v.z + v.w);
            }
            const int b_l = o >> 4, c_l = o & 15;
            const int n = n0c + c_l;
            const int j = n - 1024;
            s += xgc[(((size_t)dir * CHUNK + i) * BB + (b0 + b_l)) * G3 + n];
            float cand = tanhf(s);
            const size_t idx = ((size_t)dir * 32 + b0 + b_l) * 512 + j;
            float z = zbuf[idx], h = hbuf[idx];
            float hn = fmaf(z, h - cand, cand);   // z*h + (1-z)*cand
            hbuf[idx] = hn;
            out[((size_t)(b0 + b_l) * TT + t) * (2 * UU) + (size_t)dir * UU + j] = hn;
        }
        group_barrier(bar_arr, bar_ep, base + (unsigned)(i * 2 + 1));
    }
}

extern "C" void kernel_launch(void* const* d_in, const int* in_sizes, int n_in,
                              void* d_out, int out_size, void* d_ws, size_t ws_size,
                              hipStream_t stream) {
    const float* x  = (const float*)d_in[0];
    const float* Wf = (const float*)d_in[1];
    const float* Uf = (const float*)d_in[2];
    const float* bf = (const float*)d_in[3];
    const float* Wb = (const float*)d_in[4];
    const float* Ub = (const float*)d_in[5];
    const float* bb = (const float*)d_in[6];
    float* out = (float*)d_out;

    // ws: h[2][32][512], z, rh (384 KB) + bars (2 KB) + xg chunk buf (~25 MB)
    float* hbuf  = (float*)d_ws;
    float* zbuf  = hbuf + 2 * BB * UU;
    float* rhbuf = zbuf + 2 * BB * UU;
    unsigned* bars = (unsigned*)(rhbuf + 2 * BB * UU);
    float* xgc   = (float*)(bars + 512);

    // zero h0 + barrier state (ws is re-poisoned before every launch)
    hipMemsetAsync(d_ws, 0, (size_t)(3 * 2 * BB * UU) * sizeof(float) + 2048, stream);

    static_assert(LDS_FLOATS * 4 <= 160 * 1024, "LDS overflow");
    hipFuncSetAttribute((const void*)gru_chunk,
                        hipFuncAttributeMaxDynamicSharedMemorySize,
                        LDS_FLOATS * 4);

    for (int c = 0; c < TT / CHUNK; ++c) {
        xg_gemm<<<dim3(24, 16, 2), 256, 0, stream>>>(
            x, Wf, bf, Wb, bb, xgc, c * CHUNK);
        gru_chunk<<<dim3(256), dim3(512), LDS_FLOATS * 4, stream>>>(
            Uf, Ub, xgc, hbuf, zbuf, rhbuf, bars, out, c);
    }
}

// Round 4
// 6063.478 us; speedup vs baseline: 4.0559x; 4.0559x over previous
//
#include <hip/hip_runtime.h>
#include <math.h>

#define BB 32
#define TT 512
#define DD 512
#define UU 512
#define G3 1536   // 3*U
#define CHUNK 64  // time steps per xg chunk

__device__ __forceinline__ float hsig(float x) {
    return fminf(fmaxf(fmaf(0.2f, x, 0.5f), 0.0f), 1.0f);
}

// LLC-coherent accessors: relaxed agent-scope atomics compile to sc1
// global ops that bypass the (non-cross-XCD-coherent) L2 and hit the
// Infinity Cache directly.  No buffer_wbl2 / buffer_inv anywhere.
__device__ __forceinline__ float llc_load(const float* p) {
    return __hip_atomic_load(p, __ATOMIC_RELAXED, __HIP_MEMORY_SCOPE_AGENT);
}
__device__ __forceinline__ void llc_store(float* p, float v) {
    __hip_atomic_store(p, v, __ATOMIC_RELAXED, __HIP_MEMORY_SCOPE_AGENT);
}

// ---------------------------------------------------------------------------
// Kernel A: x_gates chunk GEMM (proven in rounds 2-3, unchanged).
// ---------------------------------------------------------------------------
__global__ __launch_bounds__(256) void xg_gemm(
    const float* __restrict__ x,
    const float* __restrict__ Wf, const float* __restrict__ bf,
    const float* __restrict__ Wb, const float* __restrict__ bb,
    float* __restrict__ xgc, int t0)
{
    const int dir = blockIdx.z;
    const int n0  = blockIdx.x * 64;
    const int m0  = blockIdx.y * 128;
    const float* W    = dir ? Wb : Wf;
    const float* bias = dir ? bb : bf;

    __shared__ float As[16][132];
    __shared__ float Bs[16][64];

    const int tid = threadIdx.x;
    const int tx = tid & 15, ty = tid >> 4;

    float acc[8][4];
    #pragma unroll
    for (int i = 0; i < 8; ++i)
        #pragma unroll
        for (int q = 0; q < 4; ++q) acc[i][q] = 0.f;

    const int lmr = tid >> 2;
    const int ak4 = (tid & 3) * 4;
    const float* arow0;
    const float* arow1;
    {
        int m = m0 + lmr;
        int b = m & 31, i = m >> 5;
        int tp = dir ? (TT - 1 - t0 - i) : (t0 + i);
        arow0 = x + ((size_t)b * TT + tp) * DD;
        m = m0 + lmr + 64;
        b = m & 31; i = m >> 5;
        tp = dir ? (TT - 1 - t0 - i) : (t0 + i);
        arow1 = x + ((size_t)b * TT + tp) * DD;
    }
    const float* bsrc = W + (size_t)(tid >> 4) * G3 + n0 + (tid & 15) * 4;

    for (int k0 = 0; k0 < DD; k0 += 16) {
        float4 a0 = *(const float4*)(arow0 + k0 + ak4);
        float4 a1 = *(const float4*)(arow1 + k0 + ak4);
        float4 bv = *(const float4*)(bsrc + (size_t)k0 * G3);
        __syncthreads();
        As[ak4 + 0][lmr] = a0.x;  As[ak4 + 1][lmr] = a0.y;
        As[ak4 + 2][lmr] = a0.z;  As[ak4 + 3][lmr] = a0.w;
        As[ak4 + 0][lmr + 64] = a1.x;  As[ak4 + 1][lmr + 64] = a1.y;
        As[ak4 + 2][lmr + 64] = a1.z;  As[ak4 + 3][lmr + 64] = a1.w;
        *(float4*)&Bs[tid >> 4][(tid & 15) * 4] = bv;
        __syncthreads();
        #pragma unroll
        for (int kk = 0; kk < 16; ++kk) {
            float4 b4 = *(const float4*)&Bs[kk][tx * 4];
            #pragma unroll
            for (int i = 0; i < 8; ++i) {
                float a = As[kk][ty * 8 + i];
                acc[i][0] = fmaf(a, b4.x, acc[i][0]);
                acc[i][1] = fmaf(a, b4.y, acc[i][1]);
                acc[i][2] = fmaf(a, b4.z, acc[i][2]);
                acc[i][3] = fmaf(a, b4.w, acc[i][3]);
            }
        }
    }

    float4 bv = *(const float4*)(bias + n0 + tx * 4);
    #pragma unroll
    for (int i = 0; i < 8; ++i) {
        int m = m0 + ty * 8 + i;
        float4 o;
        o.x = acc[i][0] + bv.x;  o.y = acc[i][1] + bv.y;
        o.z = acc[i][2] + bv.z;  o.w = acc[i][3] + bv.w;
        *(float4*)(xgc + ((size_t)dir * (CHUNK * BB) + m) * G3 + n0 + tx * 4) = o;
    }
}

// ---------------------------------------------------------------------------
// Group barrier: 32 WGs, monotone epoch, relaxed agent atomics only.
// All cross-WG data traveled via sc1 (LLC) atomics, so no cache ops needed;
// s_waitcnt 0 guarantees this WG's sc1 stores reached the LLC before arrive.
// ---------------------------------------------------------------------------
__device__ __forceinline__ void group_barrier(unsigned* arrive, unsigned* epoch,
                                              unsigned serial) {
    __syncthreads();
    if (threadIdx.x == 0) {
        __builtin_amdgcn_s_waitcnt(0);
        __asm__ volatile("" ::: "memory");
        unsigned old = __hip_atomic_fetch_add(arrive, 1u, __ATOMIC_RELAXED,
                                              __HIP_MEMORY_SCOPE_AGENT);
        if ((old & 31u) == 31u) {
            __hip_atomic_store(epoch, serial + 1u, __ATOMIC_RELAXED,
                               __HIP_MEMORY_SCOPE_AGENT);
        } else {
            while (__hip_atomic_load(epoch, __ATOMIC_RELAXED,
                                     __HIP_MEMORY_SCOPE_AGENT) < serial + 1u)
                __builtin_amdgcn_s_sleep(2);
        }
        __asm__ volatile("" ::: "memory");
    }
    __syncthreads();
}

// ---------------------------------------------------------------------------
// Persistent chunk kernel: 64 time steps of the recurrence.
// Same structure as round 3; only the cross-WG memory ops changed.
// ---------------------------------------------------------------------------
#define WSTRIDE 516
#define NWCOLS 48
#define P1RED 36
#define P2RED 68
#define LDS_FLOATS (NWCOLS * WSTRIDE + 8 * WSTRIDE + 9216)

__global__ __launch_bounds__(512, 1) void gru_chunk(
    const float* __restrict__ Uf, const float* __restrict__ Ub,
    const float* __restrict__ xgc,
    float* __restrict__ hbuf, float* __restrict__ zbuf,
    float* __restrict__ rhbuf, unsigned* __restrict__ bars,
    float* __restrict__ out, int c)
{
    extern __shared__ float lds[];
    float* Wl   = lds;
    float* hp   = Wl + NWCOLS * WSTRIDE;
    float* part = hp + 8 * WSTRIDE;

    const int tid = threadIdx.x;
    const int g   = blockIdx.x >> 5;
    const int w   = blockIdx.x & 31;
    const int dir = g >> 2;
    const int b0  = (g & 3) * 8;

    unsigned* bar_arr = bars + g * 64;
    unsigned* bar_ep  = bars + g * 64 + 32;
    const unsigned base = (unsigned)(c * 128);

    const float* U = dir ? Ub : Uf;
    const int n0z = w * 32;
    const int n0c = 1024 + w * 16;

    // ---- stage weights (once per chunk launch) ----
    for (int q = tid; q < 512 * 12; q += 512) {
        int k  = q & 511;
        int jj = q >> 9;
        int n  = (jj < 8) ? (n0z + jj * 4) : (n0c + (jj - 8) * 4);
        int cc = (jj < 8) ? jj * 4 : (32 + (jj - 8) * 4);
        float4 v = *(const float4*)(U + (size_t)k * G3 + n);
        float* wc = Wl + (size_t)cc * WSTRIDE + k;
        wc[0]           = v.x;
        wc[WSTRIDE]     = v.y;
        wc[2 * WSTRIDE] = v.z;
        wc[3 * WSTRIDE] = v.w;
    }
    __syncthreads();

    float* hg_h  = hbuf  + ((size_t)dir * 32 + b0) * 512;
    float* hg_rh = rhbuf + ((size_t)dir * 32 + b0) * 512;

    for (int i = 0; i < CHUNK; ++i) {
        const int t = c * CHUNK + i;

        // ---- stage h into hp (LLC loads) ----
        #pragma unroll
        for (int q = tid; q < 4096; q += 512) {
            int b = q >> 9, k = q & 511;
            hp[(size_t)b * WSTRIDE + k] = llc_load(hg_h + (size_t)b * 512 + k);
        }
        __syncthreads();

        // ---- phase 1 dots: z,r ----
        {
            const int cslot = tid & 7;
            const int bslot = (tid >> 3) & 1;
            const int ks    = tid >> 4;
            const int kb    = ks * 16;
            const float* wp = Wl + (size_t)cslot * WSTRIDE + kb;
            const float* hq = hp + (size_t)(bslot * 4) * WSTRIDE + kb;
            float acc[4][4];
            #pragma unroll
            for (int a = 0; a < 4; ++a)
                #pragma unroll
                for (int b = 0; b < 4; ++b) acc[a][b] = 0.f;
            #pragma unroll
            for (int kk = 0; kk < 16; kk += 4) {
                float4 wv[4], hv[4];
                #pragma unroll
                for (int ci = 0; ci < 4; ++ci)
                    wv[ci] = *(const float4*)(wp + (size_t)ci * (8 * WSTRIDE) + kk);
                #pragma unroll
                for (int bi = 0; bi < 4; ++bi)
                    hv[bi] = *(const float4*)(hq + (size_t)bi * WSTRIDE + kk);
                #pragma unroll
                for (int ci = 0; ci < 4; ++ci)
                    #pragma unroll
                    for (int bi = 0; bi < 4; ++bi) {
                        acc[ci][bi] = fmaf(wv[ci].x, hv[bi].x, acc[ci][bi]);
                        acc[ci][bi] = fmaf(wv[ci].y, hv[bi].y, acc[ci][bi]);
                        acc[ci][bi] = fmaf(wv[ci].z, hv[bi].z, acc[ci][bi]);
                        acc[ci][bi] = fmaf(wv[ci].w, hv[bi].w, acc[ci][bi]);
                    }
            }
            #pragma unroll
            for (int ci = 0; ci < 4; ++ci)
                #pragma unroll
                for (int bi = 0; bi < 4; ++bi) {
                    int o = (bslot * 4 + bi) * 32 + cslot + 8 * ci;
                    part[(size_t)o * P1RED + ks] = acc[ci][bi];
                }
        }
        __syncthreads();

        // ---- phase 1 reduce + gate epilogue (z/rh to LLC) ----
        if (tid < 256) {
            const int o = tid;
            const float* pp = part + (size_t)o * P1RED;
            float s = 0.f;
            #pragma unroll
            for (int gq = 0; gq < 8; ++gq) {
                float4 v = *(const float4*)(pp + gq * 4);
                s += (v.x + v.y) + (v.z + v.w);
            }
            const int b_l = o >> 5, c_l = o & 31;
            const int n = n0z + c_l;
            s += xgc[(((size_t)dir * CHUNK + i) * BB + (b0 + b_l)) * G3 + n];
            float gv = hsig(s);
            const size_t row = ((size_t)dir * 32 + b0 + b_l) * 512;
            if (n < 512) llc_store(zbuf + row + n, gv);
            else         llc_store(rhbuf + row + n - 512,
                                   gv * hp[(size_t)b_l * WSTRIDE + (n - 512)]);
        }
        group_barrier(bar_arr, bar_ep, base + (unsigned)(i * 2));

        // ---- stage rh into hp (LLC loads) ----
        #pragma unroll
        for (int q = tid; q < 4096; q += 512) {
            int b = q >> 9, k = q & 511;
            hp[(size_t)b * WSTRIDE + k] = llc_load(hg_rh + (size_t)b * 512 + k);
        }
        __syncthreads();

        // ---- phase 2 dots: cand ----
        {
            const int cslot = tid & 3;
            const int bslot = (tid >> 2) & 1;
            const int ks    = tid >> 3;
            const int kb    = ks * 8;
            const float* wp = Wl + (size_t)(32 + cslot) * WSTRIDE + kb;
            const float* hq = hp + (size_t)(bslot * 4) * WSTRIDE + kb;
            float acc[4][4];
            #pragma unroll
            for (int a = 0; a < 4; ++a)
                #pragma unroll
                for (int b = 0; b < 4; ++b) acc[a][b] = 0.f;
            #pragma unroll
            for (int kk = 0; kk < 8; kk += 4) {
                float4 wv[4], hv[4];
                #pragma unroll
                for (int ci = 0; ci < 4; ++ci)
                    wv[ci] = *(const float4*)(wp + (size_t)ci * (4 * WSTRIDE) + kk);
                #pragma unroll
                for (int bi = 0; bi < 4; ++bi)
                    hv[bi] = *(const float4*)(hq + (size_t)bi * WSTRIDE + kk);
                #pragma unroll
                for (int ci = 0; ci < 4; ++ci)
                    #pragma unroll
                    for (int bi = 0; bi < 4; ++bi) {
                        acc[ci][bi] = fmaf(wv[ci].x, hv[bi].x, acc[ci][bi]);
                        acc[ci][bi] = fmaf(wv[ci].y, hv[bi].y, acc[ci][bi]);
                        acc[ci][bi] = fmaf(wv[ci].z, hv[bi].z, acc[ci][bi]);
                        acc[ci][bi] = fmaf(wv[ci].w, hv[bi].w, acc[ci][bi]);
                    }
            }
            #pragma unroll
            for (int ci = 0; ci < 4; ++ci)
                #pragma unroll
                for (int bi = 0; bi < 4; ++bi) {
                    int o = (bslot * 4 + bi) * 16 + cslot + 4 * ci;
                    part[(size_t)o * P2RED + ks] = acc[ci][bi];
                }
        }
        __syncthreads();

        // ---- phase 2 reduce + h update + output ----
        if (tid < 128) {
            const int o = tid;
            const float* pp = part + (size_t)o * P2RED;
            float s = 0.f;
            #pragma unroll
            for (int gq = 0; gq < 16; ++gq) {
                float4 v = *(const float4*)(pp + gq * 4);
                s += (v.x + v.y) + (v.z + v.w);
            }
            const int b_l = o >> 4, c_l = o & 15;
            const int n = n0c + c_l;
            const int j = n - 1024;
            s += xgc[(((size_t)dir * CHUNK + i) * BB + (b0 + b_l)) * G3 + n];
            float cand = tanhf(s);
            const size_t idx = ((size_t)dir * 32 + b0 + b_l) * 512 + j;
            float z = llc_load(zbuf + idx);
            float h = llc_load(hbuf + idx);
            float hn = fmaf(z, h - cand, cand);   // z*h + (1-z)*cand
            llc_store(hbuf + idx, hn);
            out[((size_t)(b0 + b_l) * TT + t) * (2 * UU) + (size_t)dir * UU + j] = hn;
        }
        group_barrier(bar_arr, bar_ep, base + (unsigned)(i * 2 + 1));
    }
}

extern "C" void kernel_launch(void* const* d_in, const int* in_sizes, int n_in,
                              void* d_out, int out_size, void* d_ws, size_t ws_size,
                              hipStream_t stream) {
    const float* x  = (const float*)d_in[0];
    const float* Wf = (const float*)d_in[1];
    const float* Uf = (const float*)d_in[2];
    const float* bf = (const float*)d_in[3];
    const float* Wb = (const float*)d_in[4];
    const float* Ub = (const float*)d_in[5];
    const float* bb = (const float*)d_in[6];
    float* out = (float*)d_out;

    float* hbuf  = (float*)d_ws;
    float* zbuf  = hbuf + 2 * BB * UU;
    float* rhbuf = zbuf + 2 * BB * UU;
    unsigned* bars = (unsigned*)(rhbuf + 2 * BB * UU);
    float* xgc   = (float*)(bars + 512);

    hipMemsetAsync(d_ws, 0, (size_t)(3 * 2 * BB * UU) * sizeof(float) + 2048, stream);

    static_assert(LDS_FLOATS * 4 <= 160 * 1024, "LDS overflow");
    hipFuncSetAttribute((const void*)gru_chunk,
                        hipFuncAttributeMaxDynamicSharedMemorySize,
                        LDS_FLOATS * 4);

    for (int c = 0; c < TT / CHUNK; ++c) {
        xg_gemm<<<dim3(24, 16, 2), 256, 0, stream>>>(
            x, Wf, bf, Wb, bb, xgc, c * CHUNK);
        gru_chunk<<<dim3(256), dim3(512), LDS_FLOATS * 4, stream>>>(
            Uf, Ub, xgc, hbuf, zbuf, rhbuf, bars, out, c);
    }
}

// Round 5
// 5449.415 us; speedup vs baseline: 4.5130x; 1.1127x over previous
//
#include <hip/hip_runtime.h>
#include <math.h>

#define BB 32
#define TT 512
#define DD 512
#define UU 512
#define G3 1536   // 3*U
#define CHUNK 64  // time steps per xg chunk

__device__ __forceinline__ float hsig(float x) {
    return fminf(fmaxf(fmaf(0.2f, x, 0.5f), 0.0f), 1.0f);
}

// LLC-coherent accessors (sc1): bypass the non-cross-XCD-coherent L2s.
__device__ __forceinline__ float llc_load(const float* p) {
    return __hip_atomic_load(p, __ATOMIC_RELAXED, __HIP_MEMORY_SCOPE_AGENT);
}
__device__ __forceinline__ void llc_store(float* p, float v) {
    __hip_atomic_store(p, v, __ATOMIC_RELAXED, __HIP_MEMORY_SCOPE_AGENT);
}
__device__ __forceinline__ unsigned llc_load_u(const unsigned* p) {
    return __hip_atomic_load(p, __ATOMIC_RELAXED, __HIP_MEMORY_SCOPE_AGENT);
}
__device__ __forceinline__ void llc_store_u(unsigned* p, unsigned v) {
    __hip_atomic_store(p, v, __ATOMIC_RELAXED, __HIP_MEMORY_SCOPE_AGENT);
}

// ---------------------------------------------------------------------------
// Kernel A: x_gates chunk GEMM (proven rounds 2-4, unchanged).
// ---------------------------------------------------------------------------
__global__ __launch_bounds__(256) void xg_gemm(
    const float* __restrict__ x,
    const float* __restrict__ Wf, const float* __restrict__ bf,
    const float* __restrict__ Wb, const float* __restrict__ bb,
    float* __restrict__ xgc, int t0)
{
    const int dir = blockIdx.z;
    const int n0  = blockIdx.x * 64;
    const int m0  = blockIdx.y * 128;
    const float* W    = dir ? Wb : Wf;
    const float* bias = dir ? bb : bf;

    __shared__ float As[16][132];
    __shared__ float Bs[16][64];

    const int tid = threadIdx.x;
    const int tx = tid & 15, ty = tid >> 4;

    float acc[8][4];
    #pragma unroll
    for (int i = 0; i < 8; ++i)
        #pragma unroll
        for (int q = 0; q < 4; ++q) acc[i][q] = 0.f;

    const int lmr = tid >> 2;
    const int ak4 = (tid & 3) * 4;
    const float* arow0;
    const float* arow1;
    {
        int m = m0 + lmr;
        int b = m & 31, i = m >> 5;
        int tp = dir ? (TT - 1 - t0 - i) : (t0 + i);
        arow0 = x + ((size_t)b * TT + tp) * DD;
        m = m0 + lmr + 64;
        b = m & 31; i = m >> 5;
        tp = dir ? (TT - 1 - t0 - i) : (t0 + i);
        arow1 = x + ((size_t)b * TT + tp) * DD;
    }
    const float* bsrc = W + (size_t)(tid >> 4) * G3 + n0 + (tid & 15) * 4;

    for (int k0 = 0; k0 < DD; k0 += 16) {
        float4 a0 = *(const float4*)(arow0 + k0 + ak4);
        float4 a1 = *(const float4*)(arow1 + k0 + ak4);
        float4 bv = *(const float4*)(bsrc + (size_t)k0 * G3);
        __syncthreads();
        As[ak4 + 0][lmr] = a0.x;  As[ak4 + 1][lmr] = a0.y;
        As[ak4 + 2][lmr] = a0.z;  As[ak4 + 3][lmr] = a0.w;
        As[ak4 + 0][lmr + 64] = a1.x;  As[ak4 + 1][lmr + 64] = a1.y;
        As[ak4 + 2][lmr + 64] = a1.z;  As[ak4 + 3][lmr + 64] = a1.w;
        *(float4*)&Bs[tid >> 4][(tid & 15) * 4] = bv;
        __syncthreads();
        #pragma unroll
        for (int kk = 0; kk < 16; ++kk) {
            float4 b4 = *(const float4*)&Bs[kk][tx * 4];
            #pragma unroll
            for (int i = 0; i < 8; ++i) {
                float a = As[kk][ty * 8 + i];
                acc[i][0] = fmaf(a, b4.x, acc[i][0]);
                acc[i][1] = fmaf(a, b4.y, acc[i][1]);
                acc[i][2] = fmaf(a, b4.z, acc[i][2]);
                acc[i][3] = fmaf(a, b4.w, acc[i][3]);
            }
        }
    }

    float4 bv = *(const float4*)(bias + n0 + tx * 4);
    #pragma unroll
    for (int i = 0; i < 8; ++i) {
        int m = m0 + ty * 8 + i;
        float4 o;
        o.x = acc[i][0] + bv.x;  o.y = acc[i][1] + bv.y;
        o.z = acc[i][2] + bv.z;  o.w = acc[i][3] + bv.w;
        *(float4*)(xgc + ((size_t)dir * (CHUNK * BB) + m) * G3 + n0 + tx * 4) = o;
    }
}

// ---------------------------------------------------------------------------
// Flag-array group barrier: no RMW contention, no epoch broadcast.
// WG w stores `target` into its own slot; wave 0's lanes poll all 32 slots
// (one coalesced sc1 load per iteration).  Serial chain ~= 1 store + 1 observe.
// Entry __syncthreads drains each wave's vmcnt, so prior sc1 data stores are
// globally visible before the flag store.
// ---------------------------------------------------------------------------
__device__ __forceinline__ void flag_barrier(unsigned* flags, int w,
                                             unsigned target) {
    __syncthreads();
    if (threadIdx.x < 64) {
        if (threadIdx.x == 0) llc_store_u(flags + w, target);
        const unsigned* slot = flags + (threadIdx.x & 31);
        while (llc_load_u(slot) < target)
            __builtin_amdgcn_s_sleep(1);
    }
    __syncthreads();
}

// ---------------------------------------------------------------------------
// Persistent chunk kernel.  Group = 32 WGs (dir x batch-quad).  WG w owns the
// SAME j-range [w*16,(w+1)*16) for z, r, and cand columns, so z and h_old
// stay in LDS; only rh (after phase 1) and h (after phase 2) cross WGs.
// ---------------------------------------------------------------------------
#define WSTRIDE 516
#define NWCOLS 48
#define P1RED 36
#define P2RED 68
#define LDS_FLOATS (NWCOLS * WSTRIDE + 8 * WSTRIDE + 9216 + 256)

__global__ __launch_bounds__(512, 1) void gru_chunk(
    const float* __restrict__ Uf, const float* __restrict__ Ub,
    const float* __restrict__ xgc,
    float* __restrict__ hbuf, float* __restrict__ rhbuf,
    unsigned* __restrict__ bars, float* __restrict__ out, int c)
{
    extern __shared__ float lds[];
    float* Wl   = lds;                        // 48 cols * 516
    float* hp   = Wl + NWCOLS * WSTRIDE;      // 8 rows * 516 (h, then rh)
    float* part = hp + 8 * WSTRIDE;           // 9216
    float* zloc = part + 9216;                // 8*16
    float* hloc = zloc + 128;                 // 8*16

    const int tid = threadIdx.x;
    const int g   = blockIdx.x >> 5;   // group 0..7
    const int w   = blockIdx.x & 31;   // WG within group
    const int dir = g >> 2;
    const int b0  = (g & 3) * 8;

    unsigned* flags = bars + g * 32;
    const unsigned base = (unsigned)(c * 128);

    const float* U = dir ? Ub : Uf;
    const int j0 = w * 16;             // owned j-range for z, r, cand

    // ---- stage weights: cc 0..15 = Uz[:,j0+..], 16..31 = Ur, 32..47 = Uh ----
    for (int q = tid; q < 512 * 12; q += 512) {
        int k  = q & 511;
        int jj = q >> 9;                  // 0..11 (float4 spans)
        int gate = jj >> 2;               // 0=z,1=r,2=cand
        int off  = (jj & 3) * 4;
        int n  = gate * 512 + j0 + off;
        int cc = gate * 16 + off;
        float4 v = *(const float4*)(U + (size_t)k * G3 + n);
        float* wc = Wl + (size_t)cc * WSTRIDE + k;
        wc[0]           = v.x;
        wc[WSTRIDE]     = v.y;
        wc[2 * WSTRIDE] = v.z;
        wc[3 * WSTRIDE] = v.w;
    }
    __syncthreads();

    float* hg_h  = hbuf  + ((size_t)dir * 32 + b0) * 512;
    float* hg_rh = rhbuf + ((size_t)dir * 32 + b0) * 512;

    for (int i = 0; i < CHUNK; ++i) {
        const int t = c * CHUNK + i;

        // ---- stage h into hp (sc1 loads) ----
        #pragma unroll
        for (int q = tid; q < 4096; q += 512) {
            int b = q >> 9, k = q & 511;
            hp[(size_t)b * WSTRIDE + k] = llc_load(hg_h + (size_t)b * 512 + k);
        }
        __syncthreads();

        // ---- phase 1 dots: 32 cols (16 z + 16 r) x 8 batches, K=512 ----
        {
            const int cslot = tid & 7;
            const int bslot = (tid >> 3) & 1;
            const int ks    = tid >> 4;      // 0..31
            const int kb    = ks * 16;
            const float* wp = Wl + (size_t)cslot * WSTRIDE + kb;
            const float* hq = hp + (size_t)(bslot * 4) * WSTRIDE + kb;
            float acc[4][4];
            #pragma unroll
            for (int a = 0; a < 4; ++a)
                #pragma unroll
                for (int b = 0; b < 4; ++b) acc[a][b] = 0.f;
            #pragma unroll
            for (int kk = 0; kk < 16; kk += 4) {
                float4 wv[4], hv[4];
                #pragma unroll
                for (int ci = 0; ci < 4; ++ci)
                    wv[ci] = *(const float4*)(wp + (size_t)ci * (8 * WSTRIDE) + kk);
                #pragma unroll
                for (int bi = 0; bi < 4; ++bi)
                    hv[bi] = *(const float4*)(hq + (size_t)bi * WSTRIDE + kk);
                #pragma unroll
                for (int ci = 0; ci < 4; ++ci)
                    #pragma unroll
                    for (int bi = 0; bi < 4; ++bi) {
                        acc[ci][bi] = fmaf(wv[ci].x, hv[bi].x, acc[ci][bi]);
                        acc[ci][bi] = fmaf(wv[ci].y, hv[bi].y, acc[ci][bi]);
                        acc[ci][bi] = fmaf(wv[ci].z, hv[bi].z, acc[ci][bi]);
                        acc[ci][bi] = fmaf(wv[ci].w, hv[bi].w, acc[ci][bi]);
                    }
            }
            #pragma unroll
            for (int ci = 0; ci < 4; ++ci)
                #pragma unroll
                for (int bi = 0; bi < 4; ++bi) {
                    int o = (bslot * 4 + bi) * 32 + cslot + 8 * ci;
                    part[(size_t)o * P1RED + ks] = acc[ci][bi];
                }
        }
        __syncthreads();

        // ---- phase 1 reduce + epilogue: z->LDS, rh->LLC, h_old->LDS ----
        if (tid < 256) {
            const int o = tid;
            const float* pp = part + (size_t)o * P1RED;
            float s = 0.f;
            #pragma unroll
            for (int gq = 0; gq < 8; ++gq) {
                float4 v = *(const float4*)(pp + gq * 4);
                s += (v.x + v.y) + (v.z + v.w);
            }
            const int b_l = o >> 5, cc = o & 31;
            const int gate = cc >> 4;              // 0=z, 1=r
            const int jl = cc & 15;
            const int j = j0 + jl;
            const int n = gate * 512 + j;
            s += xgc[(((size_t)dir * CHUNK + i) * BB + (b0 + b_l)) * G3 + n];
            float gv = hsig(s);
            const float hval = hp[(size_t)b_l * WSTRIDE + j];
            if (gate == 0) {
                zloc[b_l * 16 + jl] = gv;
                hloc[b_l * 16 + jl] = hval;
            } else {
                llc_store(hg_rh + (size_t)b_l * 512 + j, gv * hval);
            }
        }
        flag_barrier(flags, w, base + (unsigned)(i * 2) + 1u);

        // ---- stage rh into hp (sc1 loads) ----
        #pragma unroll
        for (int q = tid; q < 4096; q += 512) {
            int b = q >> 9, k = q & 511;
            hp[(size_t)b * WSTRIDE + k] = llc_load(hg_rh + (size_t)b * 512 + k);
        }
        __syncthreads();

        // ---- phase 2 dots: 16 cand cols x 8 batches, K=512 ----
        {
            const int cslot = tid & 3;
            const int bslot = (tid >> 2) & 1;
            const int ks    = tid >> 3;      // 0..63
            const int kb    = ks * 8;
            const float* wp = Wl + (size_t)(32 + cslot) * WSTRIDE + kb;
            const float* hq = hp + (size_t)(bslot * 4) * WSTRIDE + kb;
            float acc[4][4];
            #pragma unroll
            for (int a = 0; a < 4; ++a)
                #pragma unroll
                for (int b = 0; b < 4; ++b) acc[a][b] = 0.f;
            #pragma unroll
            for (int kk = 0; kk < 8; kk += 4) {
                float4 wv[4], hv[4];
                #pragma unroll
                for (int ci = 0; ci < 4; ++ci)
                    wv[ci] = *(const float4*)(wp + (size_t)ci * (4 * WSTRIDE) + kk);
                #pragma unroll
                for (int bi = 0; bi < 4; ++bi)
                    hv[bi] = *(const float4*)(hq + (size_t)bi * WSTRIDE + kk);
                #pragma unroll
                for (int ci = 0; ci < 4; ++ci)
                    #pragma unroll
                    for (int bi = 0; bi < 4; ++bi) {
                        acc[ci][bi] = fmaf(wv[ci].x, hv[bi].x, acc[ci][bi]);
                        acc[ci][bi] = fmaf(wv[ci].y, hv[bi].y, acc[ci][bi]);
                        acc[ci][bi] = fmaf(wv[ci].z, hv[bi].z, acc[ci][bi]);
                        acc[ci][bi] = fmaf(wv[ci].w, hv[bi].w, acc[ci][bi]);
                    }
            }
            #pragma unroll
            for (int ci = 0; ci < 4; ++ci)
                #pragma unroll
                for (int bi = 0; bi < 4; ++bi) {
                    int o = (bslot * 4 + bi) * 16 + cslot + 4 * ci;
                    part[(size_t)o * P2RED + ks] = acc[ci][bi];
                }
        }
        __syncthreads();

        // ---- phase 2 reduce + h update (z, h_old from LDS) ----
        if (tid < 128) {
            const int o = tid;
            const float* pp = part + (size_t)o * P2RED;
            float s = 0.f;
            #pragma unroll
            for (int gq = 0; gq < 16; ++gq) {
                float4 v = *(const float4*)(pp + gq * 4);
                s += (v.x + v.y) + (v.z + v.w);
            }
            const int b_l = o >> 4, jl = o & 15;
            const int j = j0 + jl;
            s += xgc[(((size_t)dir * CHUNK + i) * BB + (b0 + b_l)) * G3 + 1024 + j];
            float cand = tanhf(s);
            float z = zloc[b_l * 16 + jl];
            float h = hloc[b_l * 16 + jl];
            float hn = fmaf(z, h - cand, cand);   // z*h + (1-z)*cand
            llc_store(hg_h + (size_t)b_l * 512 + j, hn);
            out[((size_t)(b0 + b_l) * TT + t) * (2 * UU) + (size_t)dir * UU + j] = hn;
        }
        flag_barrier(flags, w, base + (unsigned)(i * 2) + 2u);
    }
}

extern "C" void kernel_launch(void* const* d_in, const int* in_sizes, int n_in,
                              void* d_out, int out_size, void* d_ws, size_t ws_size,
                              hipStream_t stream) {
    const float* x  = (const float*)d_in[0];
    const float* Wf = (const float*)d_in[1];
    const float* Uf = (const float*)d_in[2];
    const float* bf = (const float*)d_in[3];
    const float* Wb = (const float*)d_in[4];
    const float* Ub = (const float*)d_in[5];
    const float* bb = (const float*)d_in[6];
    float* out = (float*)d_out;

    // ws: h[2][32][512], rh[2][32][512] (256 KB) + flags (1 KB) + xgc (~25 MB)
    float* hbuf  = (float*)d_ws;
    float* rhbuf = hbuf + 2 * BB * UU;
    unsigned* bars = (unsigned*)(rhbuf + 2 * BB * UU);
    float* xgc   = (float*)(bars + 512);

    hipMemsetAsync(d_ws, 0, (size_t)(2 * 2 * BB * UU) * sizeof(float) + 2048, stream);

    static_assert(LDS_FLOATS * 4 <= 160 * 1024, "LDS overflow");
    hipFuncSetAttribute((const void*)gru_chunk,
                        hipFuncAttributeMaxDynamicSharedMemorySize,
                        LDS_FLOATS * 4);

    for (int c = 0; c < TT / CHUNK; ++c) {
        xg_gemm<<<dim3(24, 16, 2), 256, 0, stream>>>(
            x, Wf, bf, Wb, bb, xgc, c * CHUNK);
        gru_chunk<<<dim3(256), dim3(512), LDS_FLOATS * 4, stream>>>(
            Uf, Ub, xgc, hbuf, rhbuf, bars, out, c);
    }
}